// Round 13
// baseline (561.514 us; speedup 1.0000x reference)
//
#include <hip/hip_runtime.h>
#include <hip/hip_bf16.h>

// GroupedLinear: out[s_e:e_e] = x[s_e:e_e] @ W[e]^T
// T=16384, K=2048, N=5632, E=8. fp32 in/out, bf16 MFMA compute.
// FUSED single kernel: fp32->bf16 conversion inside the 8-phase 256x256
// GEMM staging path (reg-staging: global fp32 loads -> cvt -> ds_write,
// one-phase write lag). 2D XCD ownership (R12), T2 swizzle, SGB, setprio.
// No prepass, no workspace.

#define T_TOK 16384
#define K_IN  2048
#define N_OUT 5632
#define NEXP  8

typedef __attribute__((ext_vector_type(8))) short short8;
typedef __attribute__((ext_vector_type(4))) float f32x4;
typedef unsigned short ushort_t;

__device__ __forceinline__ ushort_t f2bf(float x) {
  __hip_bfloat16 h = __float2bfloat16(x);  // RNE
  return *reinterpret_cast<ushort_t*>(&h);
}

__device__ __forceinline__ short8 cvt8(f32x4 a, f32x4 b) {
  short8 v;
  v[0] = (short)f2bf(a[0]); v[1] = (short)f2bf(a[1]);
  v[2] = (short)f2bf(a[2]); v[3] = (short)f2bf(a[3]);
  v[4] = (short)f2bf(b[0]); v[5] = (short)f2bf(b[1]);
  v[6] = (short)f2bf(b[2]); v[7] = (short)f2bf(b[3]);
  return v;
}

#define MT2 64             // 16384/256
#define NT2 22             // 5632/256
#define GRID2 (MT2 * NT2)  // 1408 = 8 XCD x 176

#define BAR() do { asm volatile("" ::: "memory"); \
                   __builtin_amdgcn_s_barrier(); \
                   asm volatile("" ::: "memory"); } while (0)
#define LGKM0() asm volatile("s_waitcnt lgkmcnt(0)" ::: "memory")
#define LDF(p, imm) (*(const short8*)((p) + (imm)))

// ---- SGB templates: VMEM_READ=0x20, DS_WRITE=0x200, DS_READ=0x100, MFMA=0x8
__device__ __forceinline__ void sgb_a() {  // 4 loads, 2 writes, 16 MFMA, 4 reads
  __builtin_amdgcn_sched_group_barrier(0x020, 4, 0);
  __builtin_amdgcn_sched_group_barrier(0x200, 2, 0);
#pragma unroll
  for (int i = 0; i < 4; ++i) {
    __builtin_amdgcn_sched_group_barrier(0x008, 4, 0);
    __builtin_amdgcn_sched_group_barrier(0x100, 1, 0);
  }
}
__device__ __forceinline__ void sgb_b() {  // 4 loads, 2 writes, 16 MFMA, 0 reads
  __builtin_amdgcn_sched_group_barrier(0x020, 4, 0);
  __builtin_amdgcn_sched_group_barrier(0x200, 2, 0);
  __builtin_amdgcn_sched_group_barrier(0x008, 16, 0);
}
__device__ __forceinline__ void sgb_c() {  // 4 loads, 2 writes, 16 MFMA, 16 reads
  __builtin_amdgcn_sched_group_barrier(0x020, 4, 0);
  __builtin_amdgcn_sched_group_barrier(0x200, 2, 0);
#pragma unroll
  for (int i = 0; i < 8; ++i) {
    __builtin_amdgcn_sched_group_barrier(0x008, 2, 0);
    __builtin_amdgcn_sched_group_barrier(0x100, 2, 0);
  }
}

template <int M0>
__device__ __forceinline__ void mma_pair(f32x4 acc[8][4], const short8 a0[2],
                                         const short8 a1[2],
                                         const short8 bF[4][2]) {
  __builtin_amdgcn_s_setprio(1);
#pragma unroll
  for (int n = 0; n < 4; ++n)
#pragma unroll
    for (int s = 0; s < 2; ++s) {
      acc[M0][n] = __builtin_amdgcn_mfma_f32_16x16x32_bf16(a0[s], bF[n][s],
                                                           acc[M0][n], 0, 0, 0);
      acc[M0 + 1][n] = __builtin_amdgcn_mfma_f32_16x16x32_bf16(
          a1[s], bF[n][s], acc[M0 + 1][n], 0, 0, 0);
    }
  __builtin_amdgcn_s_setprio(0);
}

__global__ void __launch_bounds__(512, 2) gemm_fused(
    const float* __restrict__ xf, const float* __restrict__ wf,
    const int* __restrict__ offs, float* __restrict__ out) {
  // [buf][mat 0=A/1=B][half][128 rows x 64 cols bf16] = 128 KiB
  __shared__ __align__(16) ushort_t lds[2][2][2][8192];

  // 2D XCD ownership: xcd owns tm band [8*xcd, 8*xcd+8); tn outer, tm inner.
  int bid = blockIdx.x;
  int loc = bid >> 3;                 // 0..175
  int tn = loc >> 3;                  // 0..21
  int tm = (bid & 7) * 8 + (loc & 7); // 0..63

  const int t = threadIdx.x;
  const int w = t >> 6;   // wave 0..7
  const int l = t & 63;
  const int wm = w >> 2;  // 0..1 : M-half of output
  const int wn = w & 3;   // 0..3 : N-quarter

  const int row0 = tm * 256;
  int e = 0;
#pragma unroll
  for (int i = 1; i < NEXP; ++i) e += (row0 >= offs[i]) ? 1 : 0;

  const size_t H = (size_t)128 * K_IN;  // half-tile row offset (elements)

  // ---- fp32 stage sources (inverse-swizzled cols; same indices as bf16) ----
  const size_t srow = (size_t)(2 * w) * 8 + (l >> 3);
  const int scol = ((l & 7) ^ (l >> 3)) * 8;  // element offset
  const float* const fA0 = xf + ((size_t)row0 + srow) * K_IN + scol;
  const float* const fA1 = fA0 + (size_t)8 * K_IN;
  const float* const fW0 =
      wf + (size_t)e * N_OUT * K_IN + ((size_t)(tn * 256) + srow) * K_IN + scol;
  const float* const fW1 = fW0 + (size_t)8 * K_IN;

  // staged fp32 in flight: two named sets (rule #20: static indexing only)
  f32x4 L0[4], L1[4];
#define LOADSET(L, p0, p1, ko) do {                 \
    L[0] = *(const f32x4*)((p0) + (ko));            \
    L[1] = *(const f32x4*)((p0) + (ko) + 4);        \
    L[2] = *(const f32x4*)((p1) + (ko));            \
    L[3] = *(const f32x4*)((p1) + (ko) + 4);        \
  } while (0)
#define WRITESET(L, dreg) do {                      \
    short8 v0_ = cvt8(L[0], L[1]);                  \
    short8 v1_ = cvt8(L[2], L[3]);                  \
    ushort_t* d_ = (dreg) + 2 * w * 512 + l * 8;    \
    *(short8*)d_ = v0_;                             \
    *(short8*)(d_ + 512) = v1_;                     \
  } while (0)

  f32x4 acc[8][4];
#pragma unroll
  for (int i = 0; i < 8; ++i)
#pragma unroll
    for (int j = 0; j < 4; ++j)
#pragma unroll
      for (int r = 0; r < 4; ++r) acc[i][j][r] = 0.f;

  // ---- fragment read addressing (T2 swizzle, dual s0/s1 bases) ----
  const int l15 = l & 15;
  const int kgo2 = (l >> 4) * 16;
  const int swz = (l15 & 7) << 4;
  const int fo0 = l15 * 128 + (kgo2 ^ swz);
  const int fo1 = l15 * 128 + ((64 + kgo2) ^ swz);
  const char* aP[2][2];  // [buf][s]
  const char* bP[2][2];
#pragma unroll
  for (int b = 0; b < 2; ++b) {
    aP[b][0] = (const char*)&lds[b][0][wm][0] + fo0;
    aP[b][1] = (const char*)&lds[b][0][wm][0] + fo1;
    bP[b][0] = (const char*)&lds[b][1][wn >> 1][0] + (wn & 1) * 8192 + fo0;
    bP[b][1] = (const char*)&lds[b][1][wn >> 1][0] + (wn & 1) * 8192 + fo1;
  }

#define LDA_PAIR(d0, d1, buf, m)                          \
  do {                                                    \
    d0[0] = LDF(aP[buf][0], (m) * 2048);                  \
    d0[1] = LDF(aP[buf][1], (m) * 2048);                  \
    d1[0] = LDF(aP[buf][0], ((m) + 1) * 2048);            \
    d1[1] = LDF(aP[buf][1], ((m) + 1) * 2048);            \
  } while (0)
#define LDB_ALL(dst, buf)                                 \
  do {                                                    \
    _Pragma("unroll")                                     \
    for (int n = 0; n < 4; ++n) {                         \
      dst[n][0] = LDF(bP[buf][0], n * 2048);              \
      dst[n][1] = LDF(bP[buf][1], n * 2048);              \
    }                                                     \
  } while (0)

  // ---- prologue: tile0 full + tile1.B staged; b1.A0 loads left pending ----
  LOADSET(L0, fA0, fA1, 0);
  LOADSET(L1, fA0, fA1, H);
  WRITESET(L0, &lds[0][0][0][0]); LOADSET(L0, fW0, fW1, 0);
  WRITESET(L1, &lds[0][0][1][0]); LOADSET(L1, fW0, fW1, H);
  WRITESET(L0, &lds[0][1][0][0]); LOADSET(L0, fW0, fW1, 64);
  WRITESET(L1, &lds[0][1][1][0]); LOADSET(L1, fW0, fW1, H + 64);
  WRITESET(L0, &lds[1][1][0][0]); LOADSET(L0, fA0, fA1, 64);  // b1.A0 pending
  WRITESET(L1, &lds[1][1][1][0]);
  LGKM0();
  BAR();

  short8 bF[4][2];
  short8 r0a[2], r0b[2];
  short8 r1a[2], r1b[2];
  LDB_ALL(bF, 0);
  LDA_PAIR(r0a, r0b, 0, 0);
  LDA_PAIR(r1a, r1b, 0, 2);

  // ---- steady loop: 15 iters. Odd phases write L0/load L1; even converse.
#pragma unroll 1
  for (int J = 0; J < 15; ++J) {
    const size_t kO1 = (size_t)(2 * J + 1) * 64;
    const size_t kO2 = (size_t)(2 * J + 2) * 64;
    const size_t kO3 = (size_t)(2 * J + 3) * 64;

    // R1: write b1.A0 (prev); load b1.A1; mma m0-1(b0,R0); R0<-b0.A45
    WRITESET(L0, &lds[1][0][0][0]);
    LOADSET(L1, fA0, fA1, H + kO1);
    sgb_a();
    mma_pair<0>(acc, r0a, r0b, bF);
    LDA_PAIR(r0a, r0b, 0, 4);
    LGKM0(); BAR();
    // R2: write b1.A1; load b0.B0'; mma m2-3(R1); R1<-b0.A67
    WRITESET(L1, &lds[1][0][1][0]);
    LOADSET(L0, fW0, fW1, kO2);
    sgb_a();
    mma_pair<2>(acc, r1a, r1b, bF);
    LDA_PAIR(r1a, r1b, 0, 6);
    LGKM0(); BAR();
    // R3: write b0.B0'; load b0.B1'; mma m4-5(R0)
    WRITESET(L0, &lds[0][1][0][0]);
    LOADSET(L1, fW0, fW1, H + kO2);
    sgb_b();
    mma_pair<4>(acc, r0a, r0b, bF);
    LGKM0(); BAR();
    // R4: write b0.B1'; load b0.A0'; mma m6-7(R1); switch to buf1 reads
    WRITESET(L1, &lds[0][1][1][0]);
    LOADSET(L0, fA0, fA1, kO2);
    sgb_c();
    mma_pair<6>(acc, r1a, r1b, bF);
    LDB_ALL(bF, 1);
    LDA_PAIR(r0a, r0b, 1, 0);
    LDA_PAIR(r1a, r1b, 1, 2);
    LGKM0(); BAR();
    // R5: write b0.A0'; load b0.A1'; mma m0-1(b1,R0); R0<-b1.A45
    WRITESET(L0, &lds[0][0][0][0]);
    LOADSET(L1, fA0, fA1, H + kO2);
    sgb_a();
    mma_pair<0>(acc, r0a, r0b, bF);
    LDA_PAIR(r0a, r0b, 1, 4);
    LGKM0(); BAR();
    // R6: write b0.A1'; load b1.B0''; mma m2-3(R1); R1<-b1.A67
    WRITESET(L1, &lds[0][0][1][0]);
    LOADSET(L0, fW0, fW1, kO3);
    sgb_a();
    mma_pair<2>(acc, r1a, r1b, bF);
    LDA_PAIR(r1a, r1b, 1, 6);
    LGKM0(); BAR();
    // R7: write b1.B0''; load b1.B1''; mma m4-5(R0)
    WRITESET(L0, &lds[1][1][0][0]);
    LOADSET(L1, fW0, fW1, H + kO3);
    sgb_b();
    mma_pair<4>(acc, r0a, r0b, bF);
    LGKM0(); BAR();
    // R8: write b1.B1''; load b1.A0''; mma m6-7(R1); switch to buf0' reads
    WRITESET(L1, &lds[1][1][1][0]);
    LOADSET(L0, fA0, fA1, kO3);  // = kO1 of J+1
    sgb_c();
    mma_pair<6>(acc, r1a, r1b, bF);
    LDB_ALL(bF, 0);
    LDA_PAIR(r0a, r0b, 0, 0);
    LDA_PAIR(r1a, r1b, 0, 2);
    LGKM0(); BAR();
  }

  // ---- peeled tail: J=15 (kO1 = 1984) ----
  {
    WRITESET(L0, &lds[1][0][0][0]);            // b1.A0
    LOADSET(L1, fA0, fA1, H + 1984);           // b1.A1 (last half-tile)
    sgb_a();
    mma_pair<0>(acc, r0a, r0b, bF);
    LDA_PAIR(r0a, r0b, 0, 4);
    LGKM0(); BAR();

    WRITESET(L1, &lds[1][0][1][0]);            // b1.A1
    mma_pair<2>(acc, r1a, r1b, bF);
    LDA_PAIR(r1a, r1b, 0, 6);
    LGKM0(); BAR();

    mma_pair<4>(acc, r0a, r0b, bF);
    BAR();

    mma_pair<6>(acc, r1a, r1b, bF);
    LDB_ALL(bF, 1);
    LDA_PAIR(r0a, r0b, 1, 0);
    LDA_PAIR(r1a, r1b, 1, 2);
    BAR();

    mma_pair<0>(acc, r0a, r0b, bF);
    LDA_PAIR(r0a, r0b, 1, 4);
    BAR();

    mma_pair<2>(acc, r1a, r1b, bF);
    LDA_PAIR(r1a, r1b, 1, 6);
    BAR();

    mma_pair<4>(acc, r0a, r0b, bF);
    BAR();

    mma_pair<6>(acc, r1a, r1b, bF);
  }

  // ---- epilogue: C/D layout col=lane&15, row=(lane>>4)*4+reg ----
  const int cr = (l >> 4) * 4;
  const int cc = l & 15;
  float* ob = out + (size_t)(row0 + wm * 128) * N_OUT + tn * 256 + wn * 64;
#pragma unroll
  for (int m = 0; m < 8; ++m)
#pragma unroll
    for (int n = 0; n < 4; ++n)
#pragma unroll
      for (int r = 0; r < 4; ++r)
        ob[(size_t)(m * 16 + cr + r) * N_OUT + n * 16 + cc] = acc[m][n][r];
#undef LDA_PAIR
#undef LDB_ALL
#undef LOADSET
#undef WRITESET
}

extern "C" void kernel_launch(void* const* d_in, const int* in_sizes, int n_in,
                              void* d_out, int out_size, void* d_ws, size_t ws_size,
                              hipStream_t stream) {
  const float* x = (const float*)d_in[0];
  const float* wt = (const float*)d_in[1];
  const int* offs = (const int*)d_in[2];
  float* out = (float*)d_out;
  (void)d_ws; (void)ws_size;

  gemm_fused<<<GRID2, 512, 0, stream>>>(x, wt, offs, out);
}

// Round 14
// 533.232 us; speedup vs baseline: 1.0530x; 1.0530x over previous
//
#include <hip/hip_runtime.h>
#include <hip/hip_bf16.h>

// GroupedLinear: out[s_e:e_e] = x[s_e:e_e] @ W[e]^T
// T=16384, K=2048, N=5632, E=8. fp32 in/out, bf16 MFMA compute.
// R12 structure (256x256 8-phase, 2D XCD ownership, T2 swizzle, counted
// vmcnt, cvt prepass) with 32x32x16 MFMA (2495 vs ~2142 TF ubench, half
// the instruction count). Fusion reverted (R13: -45%).

#define T_TOK 16384
#define K_IN  2048
#define N_OUT 5632
#define NEXP  8

typedef __attribute__((ext_vector_type(8))) short short8;
typedef __attribute__((ext_vector_type(4))) float f32x4;
typedef __attribute__((ext_vector_type(16))) float f32x16;
typedef unsigned short ushort_t;

__device__ __forceinline__ ushort_t f2bf(float x) {
  __hip_bfloat16 h = __float2bfloat16(x);  // RNE
  return *reinterpret_cast<ushort_t*>(&h);
}

// ---------------- fused fp32 -> bf16 conversion prepass ----------------
__global__ void __launch_bounds__(256) cvt2(const float* __restrict__ x,
                                            const float* __restrict__ w,
                                            ushort_t* __restrict__ ox,
                                            ushort_t* __restrict__ ow,
                                            int n8x, int n8t) {
  int i = blockIdx.x * blockDim.x + threadIdx.x;
  int stride = gridDim.x * blockDim.x;
  for (; i < n8t; i += stride) {
    const float* src;
    ushort_t* dst;
    int j;
    if (i < n8x) { src = x; dst = ox; j = i; }
    else         { src = w; dst = ow; j = i - n8x; }
    const float4* p = (const float4*)src + (size_t)j * 2;
    float4 a = p[0], b = p[1];
    short8 v;
    v[0] = (short)f2bf(a.x); v[1] = (short)f2bf(a.y);
    v[2] = (short)f2bf(a.z); v[3] = (short)f2bf(a.w);
    v[4] = (short)f2bf(b.x); v[5] = (short)f2bf(b.y);
    v[6] = (short)f2bf(b.z); v[7] = (short)f2bf(b.w);
    *((short8*)dst + j) = v;
  }
}

// ---------------- 256x256 8-phase GEMM, 32x32x16 MFMA ----------------
#define MT2 64             // 16384/256
#define NT2 22             // 5632/256
#define GRID2 (MT2 * NT2)  // 1408 = 8 XCD x 176

#define BAR() do { asm volatile("" ::: "memory"); \
                   __builtin_amdgcn_s_barrier(); \
                   asm volatile("" ::: "memory"); } while (0)
#define VMCNT(n) asm volatile("s_waitcnt vmcnt(" #n ")" ::: "memory")

// ---- SGB templates (MFMA=0x8, VMEM=0x10, DS_READ=0x100) ----
__device__ __forceinline__ void sgb_a() {  // 8 MFMA, 4 DS, 2 VMEM
  __builtin_amdgcn_sched_group_barrier(0x010, 2, 0);
#pragma unroll
  for (int i = 0; i < 4; ++i) {
    __builtin_amdgcn_sched_group_barrier(0x008, 2, 0);
    __builtin_amdgcn_sched_group_barrier(0x100, 1, 0);
  }
}
__device__ __forceinline__ void sgb_b() {  // 8 MFMA, 0 DS, 2 VMEM
  __builtin_amdgcn_sched_group_barrier(0x010, 2, 0);
  __builtin_amdgcn_sched_group_barrier(0x008, 8, 0);
}
__device__ __forceinline__ void sgb_c() {  // 8 MFMA, 16 DS, 2 VMEM
  __builtin_amdgcn_sched_group_barrier(0x010, 2, 0);
#pragma unroll
  for (int i = 0; i < 8; ++i) {
    __builtin_amdgcn_sched_group_barrier(0x008, 1, 0);
    __builtin_amdgcn_sched_group_barrier(0x100, 2, 0);
  }
}

template <int M>
__device__ __forceinline__ void mma_q(f32x16 acc[4][2], const short8 aF[4],
                                      const short8 bF[2][4]) {
  __builtin_amdgcn_s_setprio(1);
#pragma unroll
  for (int q = 0; q < 4; ++q)
#pragma unroll
    for (int n = 0; n < 2; ++n)
      acc[M][n] = __builtin_amdgcn_mfma_f32_32x32x16_bf16(aF[q], bF[n][q],
                                                          acc[M][n], 0, 0, 0);
  __builtin_amdgcn_s_setprio(0);
}

__global__ void __launch_bounds__(512, 2) gemm8(
    const ushort_t* __restrict__ abf, const ushort_t* __restrict__ wbf,
    const int* __restrict__ offs, float* __restrict__ out) {
  // [buf][mat 0=A/1=B][half][128 rows x 64 cols bf16] = 128 KiB
  __shared__ __align__(16) ushort_t lds[2][2][2][8192];

  // 2D XCD ownership: xcd owns tm band [8*xcd, 8*xcd+8); tn outer, tm inner.
  int bid = blockIdx.x;
  int loc = bid >> 3;                 // 0..175
  int tn = loc >> 3;                  // 0..21
  int tm = (bid & 7) * 8 + (loc & 7); // 0..63

  const int t = threadIdx.x;
  const int w = t >> 6;   // wave 0..7
  const int l = t & 63;
  const int wm = w >> 2;  // 0..1 : M-half of output
  const int wn = w & 3;   // 0..3 : N-quarter

  const int row0 = tm * 256;
  int e = 0;
#pragma unroll
  for (int i = 1; i < NEXP; ++i) e += (row0 >= offs[i]) ? 1 : 0;

  const ushort_t* aB = abf + (size_t)row0 * K_IN;
  const ushort_t* wB =
      wbf + (size_t)e * N_OUT * K_IN + (size_t)(tn * 256) * K_IN;
  const size_t H = (size_t)128 * K_IN;  // half-tile row offset in global

  // ---- hoisted stage source addressing (inverse-swizzled source cols) ----
  const size_t srow = (size_t)(2 * w) * 8 + (l >> 3);
  const int scol = ((l & 7) ^ (l >> 3)) * 8;
  const ushort_t* const sA0 = aB + srow * K_IN + scol;
  const ushort_t* const sA1 = aB + (srow + 8) * K_IN + scol;
  const ushort_t* const sW0 = wB + srow * K_IN + scol;
  const ushort_t* const sW1 = wB + (srow + 8) * K_IN + scol;

  auto stage2 = [&](const ushort_t* s0, const ushort_t* s1, ushort_t* lreg,
                    size_t ko) {
    __builtin_amdgcn_global_load_lds(
        (const __attribute__((address_space(1))) void*)(s0 + ko),
        (__attribute__((address_space(3))) void*)(lreg + (2 * w) * 512), 16, 0, 0);
    __builtin_amdgcn_global_load_lds(
        (const __attribute__((address_space(1))) void*)(s1 + ko),
        (__attribute__((address_space(3))) void*)(lreg + (2 * w + 1) * 512), 16, 0, 0);
  };

  f32x16 acc[4][2];
#pragma unroll
  for (int i = 0; i < 4; ++i)
#pragma unroll
    for (int j = 0; j < 2; ++j)
#pragma unroll
      for (int r = 0; r < 16; ++r) acc[i][j][r] = 0.f;

  // ---- 32x32 fragment read addressing ----
  // A-frag m, k-step q: lane l reads 16B at row = m*32 + (l&31),
  // byte = row*128 + ((q*32 + (l>>5)*16) ^ ((row&7)<<4));  row&7 == l&7.
  const int kh = (l >> 5) * 16;
  const int swz = (l & 7) << 4;
  int offq[4];
#pragma unroll
  for (int q = 0; q < 4; ++q) offq[q] = (q * 32 + kh) ^ swz;
  const char* aBs[2];
  const char* bBs[2];
#pragma unroll
  for (int b = 0; b < 2; ++b) {
    aBs[b] = (const char*)&lds[b][0][wm][0] + (l & 31) * 128;
    bBs[b] = (const char*)&lds[b][1][wn >> 1][0] + (wn & 1) * 8192 +
             (l & 31) * 128;
  }

#define LDA_Q(dst, buf, m)                                        \
  do {                                                            \
    _Pragma("unroll")                                             \
    for (int q = 0; q < 4; ++q)                                   \
      dst[q] = *(const short8*)(aBs[buf] + (m) * 4096 + offq[q]); \
  } while (0)
#define LDB_Q(dst, buf)                                                 \
  do {                                                                  \
    _Pragma("unroll")                                                   \
    for (int q = 0; q < 4; ++q)                                         \
      _Pragma("unroll")                                                 \
      for (int n = 0; n < 2; ++n)                                       \
        dst[n][q] = *(const short8*)(bBs[buf] + (n) * 4096 + offq[q]);  \
  } while (0)

  // ---- prologue: tile0 -> b0; tile1.B + tile1.A0 -> b1 (14 loads/wave) ----
  stage2(sA0, sA1, &lds[0][0][0][0], 0);
  stage2(sA0, sA1, &lds[0][0][1][0], H);
  stage2(sW0, sW1, &lds[0][1][0][0], 0);
  stage2(sW0, sW1, &lds[0][1][1][0], H);
  stage2(sW0, sW1, &lds[1][1][0][0], 64);
  stage2(sW0, sW1, &lds[1][1][1][0], H + 64);
  stage2(sA0, sA1, &lds[1][0][0][0], 64);  // b1.A0 @ kO1(J=0)
  VMCNT(6);  // retire tile0's 8 loads; 6 (tile1.B + tile1.A0) in flight
  BAR();

  short8 bF[2][4];
  short8 R0[4], R1[4];
  LDB_Q(bF, 0);
  LDA_Q(R0, 0, 0);
  LDA_Q(R1, 0, 1);

  // ---- steady loop: 15 iterations (stage/vmcnt schedule == R12) ----
#pragma unroll 1
  for (int J = 0; J < 15; ++J) {
    const size_t kO1 = (size_t)(2 * J + 1) * 64;
    const size_t kO2 = (size_t)(2 * J + 2) * 64;
    const size_t kO3 = (size_t)(2 * J + 3) * 64;

    // P1: mma m0(b0,R0); stage b1.A1; prefetch R0<-b0.m2
    sgb_a();
    mma_q<0>(acc, R0, bF);
    stage2(sA0, sA1, &lds[1][0][1][0], H + kO1);
    LDA_Q(R0, 0, 2);
    BAR();
    // P2: mma m1(R1); stage b0.B0'; prefetch R1<-b0.m3
    sgb_a();
    mma_q<1>(acc, R1, bF);
    stage2(sW0, sW1, &lds[0][1][0][0], kO2);
    LDA_Q(R1, 0, 3);
    BAR();
    // P3: mma m2(R0); stage b0.B1'; VMCNT(4) -> buf1 landed
    sgb_b();
    mma_q<2>(acc, R0, bF);
    stage2(sW0, sW1, &lds[0][1][1][0], H + kO2);
    VMCNT(4);
    BAR();
    // P4: mma m3(R1); LDB<-b1; R0<-b1.m0; stage b0.A0'; R1<-b1.m1
    sgb_c();
    mma_q<3>(acc, R1, bF);
    LDB_Q(bF, 1);
    LDA_Q(R0, 1, 0);
    stage2(sA0, sA1, &lds[0][0][0][0], kO2);
    LDA_Q(R1, 1, 1);
    BAR();
    // P5: mma m0(b1,R0); stage b0.A1'; prefetch R0<-b1.m2
    sgb_a();
    mma_q<0>(acc, R0, bF);
    stage2(sA0, sA1, &lds[0][0][1][0], H + kO2);
    LDA_Q(R0, 1, 2);
    BAR();
    // P6: mma m1(R1); stage b1.B0''; prefetch R1<-b1.m3
    sgb_a();
    mma_q<1>(acc, R1, bF);
    stage2(sW0, sW1, &lds[1][1][0][0], kO3);
    LDA_Q(R1, 1, 3);
    BAR();
    // P7: mma m2(R0); stage b1.B1''; VMCNT(4) -> buf0' landed
    sgb_b();
    mma_q<2>(acc, R0, bF);
    stage2(sW0, sW1, &lds[1][1][1][0], H + kO3);
    VMCNT(4);
    BAR();
    // P8: mma m3(R1); LDB<-b0'; R0<-b0'.m0; stage b1.A0''; R1<-b0'.m1
    sgb_c();
    mma_q<3>(acc, R1, bF);
    LDB_Q(bF, 0);
    LDA_Q(R0, 0, 0);
    stage2(sA0, sA1, &lds[1][0][0][0], kO3);  // = kO1 of J+1
    LDA_Q(R1, 0, 1);
    BAR();
  }

  // ---- peeled tail: J=15 (kO1 = 31*64 = 1984) ----
  {
    sgb_a();
    mma_q<0>(acc, R0, bF);
    stage2(sA0, sA1, &lds[1][0][1][0], H + 1984);  // b1.A1 (last half-tile)
    LDA_Q(R0, 0, 2);
    BAR();
    sgb_a();
    mma_q<1>(acc, R1, bF);
    LDA_Q(R1, 0, 3);
    BAR();
    sgb_b();
    mma_q<2>(acc, R0, bF);
    VMCNT(0);  // drain: buf1 fully landed
    BAR();
    sgb_c();
    mma_q<3>(acc, R1, bF);
    LDB_Q(bF, 1);
    LDA_Q(R0, 1, 0);
    LDA_Q(R1, 1, 1);
    BAR();
    sgb_a();
    mma_q<0>(acc, R0, bF);
    LDA_Q(R0, 1, 2);
    BAR();
    sgb_a();
    mma_q<1>(acc, R1, bF);
    LDA_Q(R1, 1, 3);
    BAR();
    sgb_b();
    mma_q<2>(acc, R0, bF);
    BAR();
    mma_q<3>(acc, R1, bF);
  }

  // ---- epilogue: 32x32 C/D layout col=l&31, row=(r&3)+8*(r>>2)+4*(l>>5) ----
  const int cc = l & 31;
  const int rb = 4 * (l >> 5);
  float* ob = out + (size_t)(row0 + wm * 128) * N_OUT + tn * 256 + wn * 64;
#pragma unroll
  for (int m = 0; m < 4; ++m)
#pragma unroll
    for (int n = 0; n < 2; ++n)
#pragma unroll
      for (int r = 0; r < 16; ++r)
        ob[(size_t)(m * 32 + (r & 3) + 8 * (r >> 2) + rb) * N_OUT + n * 32 +
           cc] = acc[m][n][r];
#undef LDA_Q
#undef LDB_Q
}

// ---------------- fallback (ws too small): fp32 reg-staging 128x128 ----------------
#define BM 128
#define BN 128
#define BK 64
#define MT (T_TOK / BM)
#define NTILE (N_OUT / BN)

__global__ void __launch_bounds__(256) gemm_fb(const float* __restrict__ af,
                                               const float* __restrict__ wf,
                                               const int* __restrict__ offs,
                                               float* __restrict__ out) {
  __shared__ __align__(16) ushort_t lsA[BM * BK];
  __shared__ __align__(16) ushort_t lsB[BN * BK];
  int bid = blockIdx.x;
  int wg = (bid & 7) * ((MT * NTILE) >> 3) + (bid >> 3);
  int tm = wg / NTILE, tn = wg - tm * NTILE;
  const int t = threadIdx.x, w = t >> 6, l = t & 63;
  const int row0 = tm * BM;
  int e = 0;
#pragma unroll
  for (int i = 1; i < NEXP; ++i) e += (row0 >= offs[i]) ? 1 : 0;
  const size_t wbase = (size_t)e * ((size_t)N_OUT * K_IN);
  f32x4 acc[4][4];
#pragma unroll
  for (int i = 0; i < 4; ++i)
#pragma unroll
    for (int j = 0; j < 4; ++j)
#pragma unroll
      for (int r = 0; r < 4; ++r) acc[i][j][r] = 0.f;
  const int wm = w >> 1, wn = w & 1;
  const int rA = wm * 64 + (l & 15), rB = wn * 64 + (l & 15);
  const int kgo = (l >> 4) * 8;
  for (int kt = 0; kt < K_IN / BK; ++kt) {
    const int k0 = kt * BK;
    if (kt) __syncthreads();
#pragma unroll
    for (int p = 0; p < 4; ++p) {
      const int ia = (p * 4 + w) * 64 + l;
      const float4* g = (const float4*)(af + (size_t)(row0 + (ia >> 3)) * K_IN +
                                        k0 + (ia & 7) * 8);
      float4 a = g[0], b = g[1];
      short8 v;
      v[0] = (short)f2bf(a.x); v[1] = (short)f2bf(a.y);
      v[2] = (short)f2bf(a.z); v[3] = (short)f2bf(a.w);
      v[4] = (short)f2bf(b.x); v[5] = (short)f2bf(b.y);
      v[6] = (short)f2bf(b.z); v[7] = (short)f2bf(b.w);
      *(short8*)&lsA[ia * 8] = v;
    }
#pragma unroll
    for (int p = 0; p < 4; ++p) {
      const int ib = (p * 4 + w) * 64 + l;
      const float4* g = (const float4*)(wf + wbase +
                                        (size_t)(tn * BN + (ib >> 3)) * K_IN +
                                        k0 + (ib & 7) * 8);
      float4 a = g[0], b = g[1];
      short8 v;
      v[0] = (short)f2bf(a.x); v[1] = (short)f2bf(a.y);
      v[2] = (short)f2bf(a.z); v[3] = (short)f2bf(a.w);
      v[4] = (short)f2bf(b.x); v[5] = (short)f2bf(b.y);
      v[6] = (short)f2bf(b.z); v[7] = (short)f2bf(b.w);
      *(short8*)&lsB[ib * 8] = v;
    }
    __syncthreads();
#pragma unroll
    for (int s = 0; s < 2; ++s) {
      const int ko = s * 32 + kgo;
      short8 aF[4], bFf[4];
#pragma unroll
      for (int i = 0; i < 4; ++i) aF[i] = *(const short8*)&lsA[(rA + i * 16) * BK + ko];
#pragma unroll
      for (int j = 0; j < 4; ++j) bFf[j] = *(const short8*)&lsB[(rB + j * 16) * BK + ko];
#pragma unroll
      for (int i = 0; i < 4; ++i)
#pragma unroll
        for (int j = 0; j < 4; ++j)
          acc[i][j] = __builtin_amdgcn_mfma_f32_16x16x32_bf16(aF[i], bFf[j],
                                                              acc[i][j], 0, 0, 0);
    }
  }
  const int cr = (l >> 4) * 4, cc = l & 15;
  float* ob = out + (size_t)(row0 + wm * 64) * N_OUT + tn * BN + wn * 64;
#pragma unroll
  for (int i = 0; i < 4; ++i)
#pragma unroll
    for (int j = 0; j < 4; ++j)
#pragma unroll
      for (int r = 0; r < 4; ++r)
        ob[(size_t)(i * 16 + cr + r) * N_OUT + j * 16 + cc] = acc[i][j][r];
}

extern "C" void kernel_launch(void* const* d_in, const int* in_sizes, int n_in,
                              void* d_out, int out_size, void* d_ws, size_t ws_size,
                              hipStream_t stream) {
  const float* x = (const float*)d_in[0];
  const float* wt = (const float*)d_in[1];
  const int* offs = (const int*)d_in[2];
  float* out = (float*)d_out;

  const size_t nA = (size_t)T_TOK * K_IN;
  const size_t nW = (size_t)NEXP * N_OUT * K_IN;
  const size_t need = (nA + nW) * sizeof(ushort_t);

  if (ws_size >= need) {
    ushort_t* abf = (ushort_t*)d_ws;
    ushort_t* wbf = abf + nA;
    cvt2<<<2048, 256, 0, stream>>>(x, wt, abf, wbf, (int)(nA / 8),
                                   (int)((nA + nW) / 8));
    gemm8<<<GRID2, 512, 0, stream>>>(abf, wbf, offs, out);
  } else {
    gemm_fb<<<MT * NTILE, 256, 0, stream>>>(x, wt, offs, out);
  }
}

// Round 15
// 508.483 us; speedup vs baseline: 1.1043x; 1.0487x over previous
//
#include <hip/hip_runtime.h>
#include <hip/hip_bf16.h>

// GroupedLinear: out[s_e:e_e] = x[s_e:e_e] @ W[e]^T
// T=16384, K=2048, N=5632, E=8. fp32 in/out, bf16 MFMA compute.
// R14 (256x256 8-phase, 32x32x16 MFMA, 2D XCD ownership) with FIXED
// swizzle f(row) = (row&7) ^ ((row>>3)&3): kills the 4-way bank conflict
// R14's f(row)=row&7 created between lanes reading rows differing by 8.

#define T_TOK 16384
#define K_IN  2048
#define N_OUT 5632
#define NEXP  8

typedef __attribute__((ext_vector_type(8))) short short8;
typedef __attribute__((ext_vector_type(4))) float f32x4;
typedef __attribute__((ext_vector_type(16))) float f32x16;
typedef unsigned short ushort_t;

__device__ __forceinline__ ushort_t f2bf(float x) {
  __hip_bfloat16 h = __float2bfloat16(x);  // RNE
  return *reinterpret_cast<ushort_t*>(&h);
}

// ---------------- fused fp32 -> bf16 conversion prepass ----------------
__global__ void __launch_bounds__(256) cvt2(const float* __restrict__ x,
                                            const float* __restrict__ w,
                                            ushort_t* __restrict__ ox,
                                            ushort_t* __restrict__ ow,
                                            int n8x, int n8t) {
  int i = blockIdx.x * blockDim.x + threadIdx.x;
  int stride = gridDim.x * blockDim.x;
  for (; i < n8t; i += stride) {
    const float* src;
    ushort_t* dst;
    int j;
    if (i < n8x) { src = x; dst = ox; j = i; }
    else         { src = w; dst = ow; j = i - n8x; }
    const float4* p = (const float4*)src + (size_t)j * 2;
    float4 a = p[0], b = p[1];
    short8 v;
    v[0] = (short)f2bf(a.x); v[1] = (short)f2bf(a.y);
    v[2] = (short)f2bf(a.z); v[3] = (short)f2bf(a.w);
    v[4] = (short)f2bf(b.x); v[5] = (short)f2bf(b.y);
    v[6] = (short)f2bf(b.z); v[7] = (short)f2bf(b.w);
    *((short8*)dst + j) = v;
  }
}

// ---------------- 256x256 8-phase GEMM, 32x32x16 MFMA ----------------
#define MT2 64             // 16384/256
#define NT2 22             // 5632/256
#define GRID2 (MT2 * NT2)  // 1408 = 8 XCD x 176

#define BAR() do { asm volatile("" ::: "memory"); \
                   __builtin_amdgcn_s_barrier(); \
                   asm volatile("" ::: "memory"); } while (0)
#define VMCNT(n) asm volatile("s_waitcnt vmcnt(" #n ")" ::: "memory")

// ---- SGB templates (MFMA=0x8, VMEM=0x10, DS_READ=0x100) ----
__device__ __forceinline__ void sgb_a() {  // 8 MFMA, 4 DS, 2 VMEM
  __builtin_amdgcn_sched_group_barrier(0x010, 2, 0);
#pragma unroll
  for (int i = 0; i < 4; ++i) {
    __builtin_amdgcn_sched_group_barrier(0x008, 2, 0);
    __builtin_amdgcn_sched_group_barrier(0x100, 1, 0);
  }
}
__device__ __forceinline__ void sgb_b() {  // 8 MFMA, 0 DS, 2 VMEM
  __builtin_amdgcn_sched_group_barrier(0x010, 2, 0);
  __builtin_amdgcn_sched_group_barrier(0x008, 8, 0);
}
__device__ __forceinline__ void sgb_c() {  // 8 MFMA, 16 DS, 2 VMEM
  __builtin_amdgcn_sched_group_barrier(0x010, 2, 0);
#pragma unroll
  for (int i = 0; i < 8; ++i) {
    __builtin_amdgcn_sched_group_barrier(0x008, 1, 0);
    __builtin_amdgcn_sched_group_barrier(0x100, 2, 0);
  }
}

template <int M>
__device__ __forceinline__ void mma_q(f32x16 acc[4][2], const short8 aF[4],
                                      const short8 bF[2][4]) {
  __builtin_amdgcn_s_setprio(1);
#pragma unroll
  for (int q = 0; q < 4; ++q)
#pragma unroll
    for (int n = 0; n < 2; ++n)
      acc[M][n] = __builtin_amdgcn_mfma_f32_32x32x16_bf16(aF[q], bF[n][q],
                                                          acc[M][n], 0, 0, 0);
  __builtin_amdgcn_s_setprio(0);
}

__global__ void __launch_bounds__(512, 2) gemm8(
    const ushort_t* __restrict__ abf, const ushort_t* __restrict__ wbf,
    const int* __restrict__ offs, float* __restrict__ out) {
  // [buf][mat 0=A/1=B][half][128 rows x 64 cols bf16] = 128 KiB
  __shared__ __align__(16) ushort_t lds[2][2][2][8192];

  // 2D XCD ownership: xcd owns tm band [8*xcd, 8*xcd+8); tn outer, tm inner.
  int bid = blockIdx.x;
  int loc = bid >> 3;                 // 0..175
  int tn = loc >> 3;                  // 0..21
  int tm = (bid & 7) * 8 + (loc & 7); // 0..63

  const int t = threadIdx.x;
  const int w = t >> 6;   // wave 0..7
  const int l = t & 63;
  const int wm = w >> 2;  // 0..1 : M-half of output
  const int wn = w & 3;   // 0..3 : N-quarter

  const int row0 = tm * 256;
  int e = 0;
#pragma unroll
  for (int i = 1; i < NEXP; ++i) e += (row0 >= offs[i]) ? 1 : 0;

  const ushort_t* aB = abf + (size_t)row0 * K_IN;
  const ushort_t* wB =
      wbf + (size_t)e * N_OUT * K_IN + (size_t)(tn * 256) * K_IN;
  const size_t H = (size_t)128 * K_IN;  // half-tile row offset in global

  // ---- stage sources, inverse-swizzled with f(r) = (r&7) ^ ((r>>3)&3) ----
  // srow = 16w + (l>>3): f = (l>>3) ^ (2w&3);  srow+8: f = (l>>3) ^ ((2w+1)&3)
  const size_t srow = (size_t)(2 * w) * 8 + (l >> 3);
  const int scol0 = (((l & 7) ^ (l >> 3) ^ ((2 * w) & 3))) * 8;
  const int scol1 = (((l & 7) ^ (l >> 3) ^ ((2 * w + 1) & 3))) * 8;
  const ushort_t* const sA0 = aB + srow * K_IN + scol0;
  const ushort_t* const sA1 = aB + (srow + 8) * K_IN + scol1;
  const ushort_t* const sW0 = wB + srow * K_IN + scol0;
  const ushort_t* const sW1 = wB + (srow + 8) * K_IN + scol1;

  auto stage2 = [&](const ushort_t* s0, const ushort_t* s1, ushort_t* lreg,
                    size_t ko) {
    __builtin_amdgcn_global_load_lds(
        (const __attribute__((address_space(1))) void*)(s0 + ko),
        (__attribute__((address_space(3))) void*)(lreg + (2 * w) * 512), 16, 0, 0);
    __builtin_amdgcn_global_load_lds(
        (const __attribute__((address_space(1))) void*)(s1 + ko),
        (__attribute__((address_space(3))) void*)(lreg + (2 * w + 1) * 512), 16, 0, 0);
  };

  f32x16 acc[4][2];
#pragma unroll
  for (int i = 0; i < 4; ++i)
#pragma unroll
    for (int j = 0; j < 2; ++j)
#pragma unroll
      for (int r = 0; r < 16; ++r) acc[i][j][r] = 0.f;

  // ---- 32x32 fragment read addressing ----
  // row = m*32 + (l&31) (A) / (wn&1)*64 + n*32 + (l&31) (B):
  // f = (l&7) ^ ((l>>3)&3)  (m*32, n*32, 64-offsets vanish in both bit fields)
  const int kh = (l >> 5) * 16;
  const int swz = ((l & 7) ^ ((l >> 3) & 3)) << 4;
  int offq[4];
#pragma unroll
  for (int q = 0; q < 4; ++q) offq[q] = (q * 32 + kh) ^ swz;
  const char* aBs[2];
  const char* bBs[2];
#pragma unroll
  for (int b = 0; b < 2; ++b) {
    aBs[b] = (const char*)&lds[b][0][wm][0] + (l & 31) * 128;
    bBs[b] = (const char*)&lds[b][1][wn >> 1][0] + (wn & 1) * 8192 +
             (l & 31) * 128;
  }

#define LDA_Q(dst, buf, m)                                        \
  do {                                                            \
    _Pragma("unroll")                                             \
    for (int q = 0; q < 4; ++q)                                   \
      dst[q] = *(const short8*)(aBs[buf] + (m) * 4096 + offq[q]); \
  } while (0)
#define LDB_Q(dst, buf)                                                 \
  do {                                                                  \
    _Pragma("unroll")                                                   \
    for (int q = 0; q < 4; ++q)                                         \
      _Pragma("unroll")                                                 \
      for (int n = 0; n < 2; ++n)                                       \
        dst[n][q] = *(const short8*)(bBs[buf] + (n) * 4096 + offq[q]);  \
  } while (0)

  // ---- prologue: tile0 -> b0; tile1.B + tile1.A0 -> b1 (14 loads/wave) ----
  stage2(sA0, sA1, &lds[0][0][0][0], 0);
  stage2(sA0, sA1, &lds[0][0][1][0], H);
  stage2(sW0, sW1, &lds[0][1][0][0], 0);
  stage2(sW0, sW1, &lds[0][1][1][0], H);
  stage2(sW0, sW1, &lds[1][1][0][0], 64);
  stage2(sW0, sW1, &lds[1][1][1][0], H + 64);
  stage2(sA0, sA1, &lds[1][0][0][0], 64);  // b1.A0 @ kO1(J=0)
  VMCNT(6);  // retire tile0's 8 loads; 6 (tile1.B + tile1.A0) in flight
  BAR();

  short8 bF[2][4];
  short8 R0[4], R1[4];
  LDB_Q(bF, 0);
  LDA_Q(R0, 0, 0);
  LDA_Q(R1, 0, 1);

  // ---- steady loop: 15 iterations (stage/vmcnt schedule == R12) ----
#pragma unroll 1
  for (int J = 0; J < 15; ++J) {
    const size_t kO1 = (size_t)(2 * J + 1) * 64;
    const size_t kO2 = (size_t)(2 * J + 2) * 64;
    const size_t kO3 = (size_t)(2 * J + 3) * 64;

    // P1: mma m0(b0,R0); stage b1.A1; prefetch R0<-b0.m2
    sgb_a();
    mma_q<0>(acc, R0, bF);
    stage2(sA0, sA1, &lds[1][0][1][0], H + kO1);
    LDA_Q(R0, 0, 2);
    BAR();
    // P2: mma m1(R1); stage b0.B0'; prefetch R1<-b0.m3
    sgb_a();
    mma_q<1>(acc, R1, bF);
    stage2(sW0, sW1, &lds[0][1][0][0], kO2);
    LDA_Q(R1, 0, 3);
    BAR();
    // P3: mma m2(R0); stage b0.B1'; VMCNT(4) -> buf1 landed
    sgb_b();
    mma_q<2>(acc, R0, bF);
    stage2(sW0, sW1, &lds[0][1][1][0], H + kO2);
    VMCNT(4);
    BAR();
    // P4: mma m3(R1); LDB<-b1; R0<-b1.m0; stage b0.A0'; R1<-b1.m1
    sgb_c();
    mma_q<3>(acc, R1, bF);
    LDB_Q(bF, 1);
    LDA_Q(R0, 1, 0);
    stage2(sA0, sA1, &lds[0][0][0][0], kO2);
    LDA_Q(R1, 1, 1);
    BAR();
    // P5: mma m0(b1,R0); stage b0.A1'; prefetch R0<-b1.m2
    sgb_a();
    mma_q<0>(acc, R0, bF);
    stage2(sA0, sA1, &lds[0][0][1][0], H + kO2);
    LDA_Q(R0, 1, 2);
    BAR();
    // P6: mma m1(R1); stage b1.B0''; prefetch R1<-b1.m3
    sgb_a();
    mma_q<1>(acc, R1, bF);
    stage2(sW0, sW1, &lds[1][1][0][0], kO3);
    LDA_Q(R1, 1, 3);
    BAR();
    // P7: mma m2(R0); stage b1.B1''; VMCNT(4) -> buf0' landed
    sgb_b();
    mma_q<2>(acc, R0, bF);
    stage2(sW0, sW1, &lds[1][1][1][0], H + kO3);
    VMCNT(4);
    BAR();
    // P8: mma m3(R1); LDB<-b0'; R0<-b0'.m0; stage b1.A0''; R1<-b0'.m1
    sgb_c();
    mma_q<3>(acc, R1, bF);
    LDB_Q(bF, 0);
    LDA_Q(R0, 0, 0);
    stage2(sA0, sA1, &lds[1][0][0][0], kO3);  // = kO1 of J+1
    LDA_Q(R1, 0, 1);
    BAR();
  }

  // ---- peeled tail: J=15 (kO1 = 31*64 = 1984) ----
  {
    sgb_a();
    mma_q<0>(acc, R0, bF);
    stage2(sA0, sA1, &lds[1][0][1][0], H + 1984);  // b1.A1 (last half-tile)
    LDA_Q(R0, 0, 2);
    BAR();
    sgb_a();
    mma_q<1>(acc, R1, bF);
    LDA_Q(R1, 0, 3);
    BAR();
    sgb_b();
    mma_q<2>(acc, R0, bF);
    VMCNT(0);  // drain: buf1 fully landed
    BAR();
    sgb_c();
    mma_q<3>(acc, R1, bF);
    LDB_Q(bF, 1);
    LDA_Q(R0, 1, 0);
    LDA_Q(R1, 1, 1);
    BAR();
    sgb_a();
    mma_q<0>(acc, R0, bF);
    LDA_Q(R0, 1, 2);
    BAR();
    sgb_a();
    mma_q<1>(acc, R1, bF);
    LDA_Q(R1, 1, 3);
    BAR();
    sgb_b();
    mma_q<2>(acc, R0, bF);
    BAR();
    mma_q<3>(acc, R1, bF);
  }

  // ---- epilogue: 32x32 C/D layout col=l&31, row=(r&3)+8*(r>>2)+4*(l>>5) ----
  const int cc = l & 31;
  const int rb = 4 * (l >> 5);
  float* ob = out + (size_t)(row0 + wm * 128) * N_OUT + tn * 256 + wn * 64;
#pragma unroll
  for (int m = 0; m < 4; ++m)
#pragma unroll
    for (int n = 0; n < 2; ++n)
#pragma unroll
      for (int r = 0; r < 16; ++r)
        ob[(size_t)(m * 32 + (r & 3) + 8 * (r >> 2) + rb) * N_OUT + n * 32 +
           cc] = acc[m][n][r];
#undef LDA_Q
#undef LDB_Q
}

// ---------------- fallback (ws too small): fp32 reg-staging 128x128 ----------------
#define BM 128
#define BN 128
#define BK 64
#define MT (T_TOK / BM)
#define NTILE (N_OUT / BN)

__global__ void __launch_bounds__(256) gemm_fb(const float* __restrict__ af,
                                               const float* __restrict__ wf,
                                               const int* __restrict__ offs,
                                               float* __restrict__ out) {
  __shared__ __align__(16) ushort_t lsA[BM * BK];
  __shared__ __align__(16) ushort_t lsB[BN * BK];
  int bid = blockIdx.x;
  int wg = (bid & 7) * ((MT * NTILE) >> 3) + (bid >> 3);
  int tm = wg / NTILE, tn = wg - tm * NTILE;
  const int t = threadIdx.x, w = t >> 6, l = t & 63;
  const int row0 = tm * BM;
  int e = 0;
#pragma unroll
  for (int i = 1; i < NEXP; ++i) e += (row0 >= offs[i]) ? 1 : 0;
  const size_t wbase = (size_t)e * ((size_t)N_OUT * K_IN);
  f32x4 acc[4][4];
#pragma unroll
  for (int i = 0; i < 4; ++i)
#pragma unroll
    for (int j = 0; j < 4; ++j)
#pragma unroll
      for (int r = 0; r < 4; ++r) acc[i][j][r] = 0.f;
  const int wm = w >> 1, wn = w & 1;
  const int rA = wm * 64 + (l & 15), rB = wn * 64 + (l & 15);
  const int kgo = (l >> 4) * 8;
  for (int kt = 0; kt < K_IN / BK; ++kt) {
    const int k0 = kt * BK;
    if (kt) __syncthreads();
#pragma unroll
    for (int p = 0; p < 4; ++p) {
      const int ia = (p * 4 + w) * 64 + l;
      const float4* g = (const float4*)(af + (size_t)(row0 + (ia >> 3)) * K_IN +
                                        k0 + (ia & 7) * 8);
      float4 a = g[0], b = g[1];
      short8 v;
      v[0] = (short)f2bf(a.x); v[1] = (short)f2bf(a.y);
      v[2] = (short)f2bf(a.z); v[3] = (short)f2bf(a.w);
      v[4] = (short)f2bf(b.x); v[5] = (short)f2bf(b.y);
      v[6] = (short)f2bf(b.z); v[7] = (short)f2bf(b.w);
      *(short8*)&lsA[ia * 8] = v;
    }
#pragma unroll
    for (int p = 0; p < 4; ++p) {
      const int ib = (p * 4 + w) * 64 + l;
      const float4* g = (const float4*)(wf + wbase +
                                        (size_t)(tn * BN + (ib >> 3)) * K_IN +
                                        k0 + (ib & 7) * 8);
      float4 a = g[0], b = g[1];
      short8 v;
      v[0] = (short)f2bf(a.x); v[1] = (short)f2bf(a.y);
      v[2] = (short)f2bf(a.z); v[3] = (short)f2bf(a.w);
      v[4] = (short)f2bf(b.x); v[5] = (short)f2bf(b.y);
      v[6] = (short)f2bf(b.z); v[7] = (short)f2bf(b.w);
      *(short8*)&lsB[ib * 8] = v;
    }
    __syncthreads();
#pragma unroll
    for (int s = 0; s < 2; ++s) {
      const int ko = s * 32 + kgo;
      short8 aF[4], bFf[4];
#pragma unroll
      for (int i = 0; i < 4; ++i) aF[i] = *(const short8*)&lsA[(rA + i * 16) * BK + ko];
#pragma unroll
      for (int j = 0; j < 4; ++j) bFf[j] = *(const short8*)&lsB[(rB + j * 16) * BK + ko];
#pragma unroll
      for (int i = 0; i < 4; ++i)
#pragma unroll
        for (int j = 0; j < 4; ++j)
          acc[i][j] = __builtin_amdgcn_mfma_f32_16x16x32_bf16(aF[i], bFf[j],
                                                              acc[i][j], 0, 0, 0);
    }
  }
  const int cr = (l >> 4) * 4, cc = l & 15;
  float* ob = out + (size_t)(row0 + wm * 64) * N_OUT + tn * BN + wn * 64;
#pragma unroll
  for (int i = 0; i < 4; ++i)
#pragma unroll
    for (int j = 0; j < 4; ++j)
#pragma unroll
      for (int r = 0; r < 4; ++r)
        ob[(size_t)(i * 16 + cr + r) * N_OUT + j * 16 + cc] = acc[i][j][r];
}

extern "C" void kernel_launch(void* const* d_in, const int* in_sizes, int n_in,
                              void* d_out, int out_size, void* d_ws, size_t ws_size,
                              hipStream_t stream) {
  const float* x = (const float*)d_in[0];
  const float* wt = (const float*)d_in[1];
  const int* offs = (const int*)d_in[2];
  float* out = (float*)d_out;

  const size_t nA = (size_t)T_TOK * K_IN;
  const size_t nW = (size_t)NEXP * N_OUT * K_IN;
  const size_t need = (nA + nW) * sizeof(ushort_t);

  if (ws_size >= need) {
    ushort_t* abf = (ushort_t*)d_ws;
    ushort_t* wbf = abf + nA;
    cvt2<<<2048, 256, 0, stream>>>(x, wt, abf, wbf, (int)(nA / 8),
                                   (int)((nA + nW) / 8));
    gemm8<<<GRID2, 512, 0, stream>>>(abf, wbf, offs, out);
  } else {
    gemm_fb<<<MT * NTILE, 256, 0, stream>>>(x, wt, offs, out);
  }
}

// Round 16
// 478.049 us; speedup vs baseline: 1.1746x; 1.0637x over previous
//
#include <hip/hip_runtime.h>
#include <hip/hip_bf16.h>

// GroupedLinear: out[s_e:e_e] = x[s_e:e_e] @ W[e]^T
// T=16384, K=2048, N=5632, E=8. fp32 in/out, bf16 MFMA compute.
// R12 REVERT (best measured: 477.65 us total; gemm 354 us, FETCH 344 MB):
// 256x256 8-phase, 16x16x32 MFMA, T2 swizzle, SGB, counted vmcnt,
// 2D XCD ownership (8-tm band per XCD, tn outer / tm inner).
// Falsified since: 32x32 MFMA (R14/15), fusion (R13), NT hints (R11).

#define T_TOK 16384
#define K_IN  2048
#define N_OUT 5632
#define NEXP  8

typedef __attribute__((ext_vector_type(8))) short short8;
typedef __attribute__((ext_vector_type(4))) float f32x4;
typedef unsigned short ushort_t;

__device__ __forceinline__ ushort_t f2bf(float x) {
  __hip_bfloat16 h = __float2bfloat16(x);  // RNE
  return *reinterpret_cast<ushort_t*>(&h);
}

// ---------------- fused fp32 -> bf16 conversion prepass ----------------
__global__ void __launch_bounds__(256) cvt2(const float* __restrict__ x,
                                            const float* __restrict__ w,
                                            ushort_t* __restrict__ ox,
                                            ushort_t* __restrict__ ow,
                                            int n8x, int n8t) {
  int i = blockIdx.x * blockDim.x + threadIdx.x;
  int stride = gridDim.x * blockDim.x;
  for (; i < n8t; i += stride) {
    const float* src;
    ushort_t* dst;
    int j;
    if (i < n8x) { src = x; dst = ox; j = i; }
    else         { src = w; dst = ow; j = i - n8x; }
    const float4* p = (const float4*)src + (size_t)j * 2;
    float4 a = p[0], b = p[1];
    short8 v;
    v[0] = (short)f2bf(a.x); v[1] = (short)f2bf(a.y);
    v[2] = (short)f2bf(a.z); v[3] = (short)f2bf(a.w);
    v[4] = (short)f2bf(b.x); v[5] = (short)f2bf(b.y);
    v[6] = (short)f2bf(b.z); v[7] = (short)f2bf(b.w);
    *((short8*)dst + j) = v;
  }
}

// ---------------- 256x256 8-phase GEMM ----------------
#define MT2 64             // 16384/256
#define NT2 22             // 5632/256
#define GRID2 (MT2 * NT2)  // 1408 = 8 XCD x 176

#define BAR() do { asm volatile("" ::: "memory"); \
                   __builtin_amdgcn_s_barrier(); \
                   asm volatile("" ::: "memory"); } while (0)
#define VMCNT(n) asm volatile("s_waitcnt vmcnt(" #n ")" ::: "memory")
#define LDF(p, imm) (*(const short8*)((p) + (imm)))

// ---- T19 region templates (masks: MFMA=0x8, VMEM=0x10, DS_READ=0x100) ----
__device__ __forceinline__ void sgb_x() {  // 16 MFMA, 4 DS, 2 VMEM
  __builtin_amdgcn_sched_group_barrier(0x010, 2, 0);
#pragma unroll
  for (int i = 0; i < 4; ++i) {
    __builtin_amdgcn_sched_group_barrier(0x008, 4, 0);
    __builtin_amdgcn_sched_group_barrier(0x100, 1, 0);
  }
}
__device__ __forceinline__ void sgb_y() {  // 16 MFMA, 0 DS, 2 VMEM
  __builtin_amdgcn_sched_group_barrier(0x010, 2, 0);
  __builtin_amdgcn_sched_group_barrier(0x008, 16, 0);
}
__device__ __forceinline__ void sgb_z() {  // 16 MFMA, 16 DS, 2 VMEM
  __builtin_amdgcn_sched_group_barrier(0x010, 2, 0);
#pragma unroll
  for (int i = 0; i < 8; ++i) {
    __builtin_amdgcn_sched_group_barrier(0x008, 2, 0);
    __builtin_amdgcn_sched_group_barrier(0x100, 2, 0);
  }
}

template <int M0>
__device__ __forceinline__ void mma_pair(f32x4 acc[8][4], const short8 a0[2],
                                         const short8 a1[2],
                                         const short8 bF[4][2]) {
  __builtin_amdgcn_s_setprio(1);
#pragma unroll
  for (int n = 0; n < 4; ++n)
#pragma unroll
    for (int s = 0; s < 2; ++s) {
      acc[M0][n] = __builtin_amdgcn_mfma_f32_16x16x32_bf16(a0[s], bF[n][s],
                                                           acc[M0][n], 0, 0, 0);
      acc[M0 + 1][n] = __builtin_amdgcn_mfma_f32_16x16x32_bf16(
          a1[s], bF[n][s], acc[M0 + 1][n], 0, 0, 0);
    }
  __builtin_amdgcn_s_setprio(0);
}

__global__ void __launch_bounds__(512, 2) gemm8(
    const ushort_t* __restrict__ abf, const ushort_t* __restrict__ wbf,
    const int* __restrict__ offs, float* __restrict__ out) {
  // [buf][mat 0=A/1=B][half][128 rows x 64 cols bf16] = 128 KiB
  __shared__ __align__(16) ushort_t lds[2][2][2][8192];

  // 2D XCD ownership: xcd owns tm band [8*xcd, 8*xcd+8); tn outer, tm inner.
  int bid = blockIdx.x;
  int loc = bid >> 3;                 // 0..175
  int tn = loc >> 3;                  // 0..21
  int tm = (bid & 7) * 8 + (loc & 7); // 0..63

  const int t = threadIdx.x;
  const int w = t >> 6;   // wave 0..7
  const int l = t & 63;
  const int wm = w >> 2;  // 0..1 : M-half of output
  const int wn = w & 3;   // 0..3 : N-quarter

  const int row0 = tm * 256;
  int e = 0;
#pragma unroll
  for (int i = 1; i < NEXP; ++i) e += (row0 >= offs[i]) ? 1 : 0;

  const ushort_t* aB = abf + (size_t)row0 * K_IN;
  const ushort_t* wB =
      wbf + (size_t)e * N_OUT * K_IN + (size_t)(tn * 256) * K_IN;
  const size_t H = (size_t)128 * K_IN;  // half-tile row offset in global

  // ---- hoisted stage source addressing (inverse-swizzled source cols) ----
  const size_t srow = (size_t)(2 * w) * 8 + (l >> 3);
  const int scol = ((l & 7) ^ (l >> 3)) * 8;
  const ushort_t* const sA0 = aB + srow * K_IN + scol;
  const ushort_t* const sA1 = aB + (srow + 8) * K_IN + scol;
  const ushort_t* const sW0 = wB + srow * K_IN + scol;
  const ushort_t* const sW1 = wB + (srow + 8) * K_IN + scol;

  auto stage2 = [&](const ushort_t* s0, const ushort_t* s1, ushort_t* lreg,
                    size_t ko) {
    __builtin_amdgcn_global_load_lds(
        (const __attribute__((address_space(1))) void*)(s0 + ko),
        (__attribute__((address_space(3))) void*)(lreg + (2 * w) * 512), 16, 0, 0);
    __builtin_amdgcn_global_load_lds(
        (const __attribute__((address_space(1))) void*)(s1 + ko),
        (__attribute__((address_space(3))) void*)(lreg + (2 * w + 1) * 512), 16, 0, 0);
  };

  f32x4 acc[8][4];
#pragma unroll
  for (int i = 0; i < 8; ++i)
#pragma unroll
    for (int j = 0; j < 4; ++j)
#pragma unroll
      for (int r = 0; r < 4; ++r) acc[i][j][r] = 0.f;

  // ---- hoisted fragment addressing ----
  const int l15 = l & 15;
  const int kgo2 = (l >> 4) * 16;
  const int swz = (l15 & 7) << 4;
  const int fo0 = l15 * 128 + (kgo2 ^ swz);
  const int fo1 = l15 * 128 + ((64 + kgo2) ^ swz);
  const char* aP[2][2];  // [buf][s]
  const char* bP[2][2];
#pragma unroll
  for (int b = 0; b < 2; ++b) {
    aP[b][0] = (const char*)&lds[b][0][wm][0] + fo0;
    aP[b][1] = (const char*)&lds[b][0][wm][0] + fo1;
    bP[b][0] = (const char*)&lds[b][1][wn >> 1][0] + (wn & 1) * 8192 + fo0;
    bP[b][1] = (const char*)&lds[b][1][wn >> 1][0] + (wn & 1) * 8192 + fo1;
  }

#define LDA_PAIR(d0, d1, buf, m)                          \
  do {                                                    \
    d0[0] = LDF(aP[buf][0], (m) * 2048);                  \
    d0[1] = LDF(aP[buf][1], (m) * 2048);                  \
    d1[0] = LDF(aP[buf][0], ((m) + 1) * 2048);            \
    d1[1] = LDF(aP[buf][1], ((m) + 1) * 2048);            \
  } while (0)
#define LDB_ALL(dst, buf)                                 \
  do {                                                    \
    _Pragma("unroll")                                     \
    for (int n = 0; n < 4; ++n) {                         \
      dst[n][0] = LDF(bP[buf][0], n * 2048);              \
      dst[n][1] = LDF(bP[buf][1], n * 2048);              \
    }                                                     \
  } while (0)

  // ---- prologue: tile0 -> b0; tile1.B + tile1.A0 -> b1 (14 loads/wave) ----
  stage2(sA0, sA1, &lds[0][0][0][0], 0);
  stage2(sA0, sA1, &lds[0][0][1][0], H);
  stage2(sW0, sW1, &lds[0][1][0][0], 0);
  stage2(sW0, sW1, &lds[0][1][1][0], H);
  stage2(sW0, sW1, &lds[1][1][0][0], 64);
  stage2(sW0, sW1, &lds[1][1][1][0], H + 64);
  stage2(sA0, sA1, &lds[1][0][0][0], 64);  // b1.A0 @ kO1(J=0)
  VMCNT(6);  // retire tile0's 8 loads; 6 (tile1.B + tile1.A0) in flight
  BAR();

  short8 bF[4][2];
  short8 r0a[2], r0b[2];
  short8 r1a[2], r1b[2];
  LDB_ALL(bF, 0);
  LDA_PAIR(r0a, r0b, 0, 0);
  LDA_PAIR(r1a, r1b, 0, 2);

  // ---- steady loop: 15 iterations, straight-line regions ----
#pragma unroll 1
  for (int J = 0; J < 15; ++J) {
    const size_t kO1 = (size_t)(2 * J + 1) * 64;
    const size_t kO2 = (size_t)(2 * J + 2) * 64;
    const size_t kO3 = (size_t)(2 * J + 3) * 64;

    // R1: mma m0-1(b0,R0); stage b1.A1; prefetch R0<-b0.A45
    sgb_x();
    mma_pair<0>(acc, r0a, r0b, bF);
    stage2(sA0, sA1, &lds[1][0][1][0], H + kO1);
    LDA_PAIR(r0a, r0b, 0, 4);
    BAR();
    // R2: mma m2-3(R1); stage b0.B0'; prefetch R1<-b0.A67
    sgb_x();
    mma_pair<2>(acc, r1a, r1b, bF);
    stage2(sW0, sW1, &lds[0][1][0][0], kO2);
    LDA_PAIR(r1a, r1b, 0, 6);
    BAR();
    // R3: mma m4-5(R0); stage b0.B1'; VMCNT(4) -> buf1 landed
    sgb_y();
    mma_pair<4>(acc, r0a, r0b, bF);
    stage2(sW0, sW1, &lds[0][1][1][0], H + kO2);
    VMCNT(4);
    BAR();
    // R4: mma m6-7(R1); LDB<-b1; R0<-b1.A01; stage b0.A0'; R1<-b1.A23
    sgb_z();
    mma_pair<6>(acc, r1a, r1b, bF);
    LDB_ALL(bF, 1);
    LDA_PAIR(r0a, r0b, 1, 0);
    stage2(sA0, sA1, &lds[0][0][0][0], kO2);
    LDA_PAIR(r1a, r1b, 1, 2);
    BAR();
    // R5: mma m0-1(b1,R0); stage b0.A1'; prefetch R0<-b1.A45
    sgb_x();
    mma_pair<0>(acc, r0a, r0b, bF);
    stage2(sA0, sA1, &lds[0][0][1][0], H + kO2);
    LDA_PAIR(r0a, r0b, 1, 4);
    BAR();
    // R6: mma m2-3(R1); stage b1.B0''; prefetch R1<-b1.A67
    sgb_x();
    mma_pair<2>(acc, r1a, r1b, bF);
    stage2(sW0, sW1, &lds[1][1][0][0], kO3);
    LDA_PAIR(r1a, r1b, 1, 6);
    BAR();
    // R7: mma m4-5(R0); stage b1.B1''; VMCNT(4) -> buf0' landed
    sgb_y();
    mma_pair<4>(acc, r0a, r0b, bF);
    stage2(sW0, sW1, &lds[1][1][1][0], H + kO3);
    VMCNT(4);
    BAR();
    // R8: mma m6-7(R1); LDB<-b0'; R0<-b0'.A01; stage b1.A0''; R1<-b0'.A23
    sgb_z();
    mma_pair<6>(acc, r1a, r1b, bF);
    LDB_ALL(bF, 0);
    LDA_PAIR(r0a, r0b, 0, 0);
    stage2(sA0, sA1, &lds[1][0][0][0], kO3);  // = kO1 of J+1
    LDA_PAIR(r1a, r1b, 0, 2);
    BAR();
  }

  // ---- peeled tail: J=15 (kO1 = 31*64 = 1984) ----
  {
    sgb_x();
    mma_pair<0>(acc, r0a, r0b, bF);
    stage2(sA0, sA1, &lds[1][0][1][0], H + 1984);  // b1.A1 (last half-tile)
    LDA_PAIR(r0a, r0b, 0, 4);
    BAR();
    sgb_x();
    mma_pair<2>(acc, r1a, r1b, bF);
    LDA_PAIR(r1a, r1b, 0, 6);
    BAR();
    sgb_y();
    mma_pair<4>(acc, r0a, r0b, bF);
    VMCNT(0);  // drain: buf1 fully landed
    BAR();
    sgb_z();
    mma_pair<6>(acc, r1a, r1b, bF);
    LDB_ALL(bF, 1);
    LDA_PAIR(r0a, r0b, 1, 0);
    LDA_PAIR(r1a, r1b, 1, 2);
    BAR();
    sgb_x();
    mma_pair<0>(acc, r0a, r0b, bF);
    LDA_PAIR(r0a, r0b, 1, 4);
    BAR();
    sgb_x();
    mma_pair<2>(acc, r1a, r1b, bF);
    LDA_PAIR(r1a, r1b, 1, 6);
    BAR();
    sgb_y();
    mma_pair<4>(acc, r0a, r0b, bF);
    BAR();
    mma_pair<6>(acc, r1a, r1b, bF);
  }

  // ---- epilogue: C/D layout col=lane&15, row=(lane>>4)*4+reg ----
  const int cr = (l >> 4) * 4;
  const int cc = l & 15;
  float* ob = out + (size_t)(row0 + wm * 128) * N_OUT + tn * 256 + wn * 64;
#pragma unroll
  for (int m = 0; m < 8; ++m)
#pragma unroll
    for (int n = 0; n < 4; ++n)
#pragma unroll
      for (int r = 0; r < 4; ++r)
        ob[(size_t)(m * 16 + cr + r) * N_OUT + n * 16 + cc] = acc[m][n][r];
#undef LDA_PAIR
#undef LDB_ALL
}

// ---------------- fallback (ws too small): fp32 reg-staging 128x128 ----------------
#define BM 128
#define BN 128
#define BK 64
#define MT (T_TOK / BM)
#define NTILE (N_OUT / BN)

__global__ void __launch_bounds__(256) gemm_fb(const float* __restrict__ af,
                                               const float* __restrict__ wf,
                                               const int* __restrict__ offs,
                                               float* __restrict__ out) {
  __shared__ __align__(16) ushort_t lsA[BM * BK];
  __shared__ __align__(16) ushort_t lsB[BN * BK];
  int bid = blockIdx.x;
  int wg = (bid & 7) * ((MT * NTILE) >> 3) + (bid >> 3);
  int tm = wg / NTILE, tn = wg - tm * NTILE;
  const int t = threadIdx.x, w = t >> 6, l = t & 63;
  const int row0 = tm * BM;
  int e = 0;
#pragma unroll
  for (int i = 1; i < NEXP; ++i) e += (row0 >= offs[i]) ? 1 : 0;
  const size_t wbase = (size_t)e * ((size_t)N_OUT * K_IN);
  f32x4 acc[4][4];
#pragma unroll
  for (int i = 0; i < 4; ++i)
#pragma unroll
    for (int j = 0; j < 4; ++j)
#pragma unroll
      for (int r = 0; r < 4; ++r) acc[i][j][r] = 0.f;
  const int wm = w >> 1, wn = w & 1;
  const int rA = wm * 64 + (l & 15), rB = wn * 64 + (l & 15);
  const int kgo = (l >> 4) * 8;
  for (int kt = 0; kt < K_IN / BK; ++kt) {
    const int k0 = kt * BK;
    if (kt) __syncthreads();
#pragma unroll
    for (int p = 0; p < 4; ++p) {
      const int ia = (p * 4 + w) * 64 + l;
      const float4* g = (const float4*)(af + (size_t)(row0 + (ia >> 3)) * K_IN +
                                        k0 + (ia & 7) * 8);
      float4 a = g[0], b = g[1];
      short8 v;
      v[0] = (short)f2bf(a.x); v[1] = (short)f2bf(a.y);
      v[2] = (short)f2bf(a.z); v[3] = (short)f2bf(a.w);
      v[4] = (short)f2bf(b.x); v[5] = (short)f2bf(b.y);
      v[6] = (short)f2bf(b.z); v[7] = (short)f2bf(b.w);
      *(short8*)&lsA[ia * 8] = v;
    }
#pragma unroll
    for (int p = 0; p < 4; ++p) {
      const int ib = (p * 4 + w) * 64 + l;
      const float4* g = (const float4*)(wf + wbase +
                                        (size_t)(tn * BN + (ib >> 3)) * K_IN +
                                        k0 + (ib & 7) * 8);
      float4 a = g[0], b = g[1];
      short8 v;
      v[0] = (short)f2bf(a.x); v[1] = (short)f2bf(a.y);
      v[2] = (short)f2bf(a.z); v[3] = (short)f2bf(a.w);
      v[4] = (short)f2bf(b.x); v[5] = (short)f2bf(b.y);
      v[6] = (short)f2bf(b.z); v[7] = (short)f2bf(b.w);
      *(short8*)&lsB[ib * 8] = v;
    }
    __syncthreads();
#pragma unroll
    for (int s = 0; s < 2; ++s) {
      const int ko = s * 32 + kgo;
      short8 aF[4], bFf[4];
#pragma unroll
      for (int i = 0; i < 4; ++i) aF[i] = *(const short8*)&lsA[(rA + i * 16) * BK + ko];
#pragma unroll
      for (int j = 0; j < 4; ++j) bFf[j] = *(const short8*)&lsB[(rB + j * 16) * BK + ko];
#pragma unroll
      for (int i = 0; i < 4; ++i)
#pragma unroll
        for (int j = 0; j < 4; ++j)
          acc[i][j] = __builtin_amdgcn_mfma_f32_16x16x32_bf16(aF[i], bFf[j],
                                                              acc[i][j], 0, 0, 0);
    }
  }
  const int cr = (l >> 4) * 4, cc = l & 15;
  float* ob = out + (size_t)(row0 + wm * 64) * N_OUT + tn * BN + wn * 64;
#pragma unroll
  for (int i = 0; i < 4; ++i)
#pragma unroll
    for (int j = 0; j < 4; ++j)
#pragma unroll
      for (int r = 0; r < 4; ++r)
        ob[(size_t)(i * 16 + cr + r) * N_OUT + j * 16 + cc] = acc[i][j][r];
}

extern "C" void kernel_launch(void* const* d_in, const int* in_sizes, int n_in,
                              void* d_out, int out_size, void* d_ws, size_t ws_size,
                              hipStream_t stream) {
  const float* x = (const float*)d_in[0];
  const float* wt = (const float*)d_in[1];
  const int* offs = (const int*)d_in[2];
  float* out = (float*)d_out;

  const size_t nA = (size_t)T_TOK * K_IN;
  const size_t nW = (size_t)NEXP * N_OUT * K_IN;
  const size_t need = (nA + nW) * sizeof(ushort_t);

  if (ws_size >= need) {
    ushort_t* abf = (ushort_t*)d_ws;
    ushort_t* wbf = abf + nA;
    cvt2<<<2048, 256, 0, stream>>>(x, wt, abf, wbf, (int)(nA / 8),
                                   (int)((nA + nW) / 8));
    gemm8<<<GRID2, 512, 0, stream>>>(abf, wbf, offs, out);
  } else {
    gemm_fb<<<MT * NTILE, 256, 0, stream>>>(x, wt, offs, out);
  }
}